// Round 4
// baseline (208.968 us; speedup 1.0000x reference)
//
#include <hip/hip_runtime.h>
#include <hip/hip_bf16.h>

#define LRELU(val) ((val) >= 0.0f ? (val) : 0.01f * (val))

__device__ __forceinline__ float dot4(float4 a, float4 b, float acc) {
    return fmaf(a.x, b.x, fmaf(a.y, b.y, fmaf(a.z, b.z, fmaf(a.w, b.w, acc))));
}

__device__ __forceinline__ float wdot4(const float* __restrict__ wbase, int c, int q,
                                       float4 a, float acc) {
    acc = fmaf(a.x, wbase[(4 * q + 0) * 32 + c], acc);
    acc = fmaf(a.y, wbase[(4 * q + 1) * 32 + c], acc);
    acc = fmaf(a.z, wbase[(4 * q + 2) * 32 + c], acc);
    acc = fmaf(a.w, wbase[(4 * q + 3) * 32 + c], acc);
    return acc;
}

__device__ inline int lower_bound_i(const int* __restrict__ a, int n, int v) {
    int lo = 0, hi = n;
    while (lo < hi) {
        int m = (lo + hi) >> 1;
        if (a[m] < v) lo = m + 1; else hi = m;
    }
    return lo;
}

// Sortable 32-bit distance key from the QUAD-MAJOR transposed array:
// srcT4[q*Ns + j] = float4 of dims 4q..4q+3 of node j. Lane L reads node
// j = start+L+64s -> consecutive lanes, 16B stride. dot accumulation =
// validated dot4 order.
__device__ __forceinline__ unsigned slot_key_T4(
    int s, int lane, int start, int len, int Ns,
    const float4* __restrict__ srcT4, const float* __restrict__ srcn, float ni,
    float4 x0, float4 x1, float4 x2, float4 x3,
    float4 x4, float4 x5, float4 x6, float4 x7)
{
    const int o = lane + 64 * s;
    const bool valid = o < len;
    const int j = valid ? (start + o) : min(start, Ns - 1);
    float dot = 0.0f;
    dot = dot4(srcT4[0 * Ns + j], x0, dot);
    dot = dot4(srcT4[1 * Ns + j], x1, dot);
    dot = dot4(srcT4[2 * Ns + j], x2, dot);
    dot = dot4(srcT4[3 * Ns + j], x3, dot);
    dot = dot4(srcT4[4 * Ns + j], x4, dot);
    dot = dot4(srcT4[5 * Ns + j], x5, dot);
    dot = dot4(srcT4[6 * Ns + j], x6, dot);
    dot = dot4(srcT4[7 * Ns + j], x7, dot);
    const float d2 = (ni + srcn[j]) - 2.0f * dot;   // reference distance formula
    unsigned u = __float_as_uint(d2);
    u = (d2 < 0.0f) ? ~u : (u | 0x80000000u);       // monotone float->uint map
    return valid ? u : 0xFFFFFFFFu;
}

// Membership + compaction for one node (exact lax.top_k tie semantics).
// UNCHANGED (validated): T = 16th-smallest key; ties broken by slot-major,
// lane-minor order = ascending candidate index.
template <int NSL>
__device__ __forceinline__ void select_compact(
    unsigned k0, unsigned k1, unsigned k2, unsigned k3, unsigned k4, unsigned k5,
    unsigned T, int start, int Ns, int* __restrict__ widxW, int lane)
{
    const unsigned long long below = (1ull << lane) - 1ull;
    int m = __popcll(__ballot(k0 < T));
    if (NSL > 1) m += __popcll(__ballot(k1 < T));
    if (NSL > 2) m += __popcll(__ballot(k2 < T));
    if (NSL > 3) m += __popcll(__ballot(k3 < T));
    if (NSL > 4) m += __popcll(__ballot(k4 < T));
    if (NSL > 5) m += __popcll(__ballot(k5 < T));
    const int need = 16 - m;
    const unsigned long long e0 = __ballot(k0 == T);
    const unsigned long long e1 = (NSL > 1) ? __ballot(k1 == T) : 0ull;
    const unsigned long long e2 = (NSL > 2) ? __ballot(k2 == T) : 0ull;
    const unsigned long long e3 = (NSL > 3) ? __ballot(k3 == T) : 0ull;
    const unsigned long long e4 = (NSL > 4) ? __ballot(k4 == T) : 0ull;
    const int eq0 = __popcll(e0), eq1 = eq0 + __popcll(e1), eq2 = eq1 + __popcll(e2),
              eq3 = eq2 + __popcll(e3), eq4 = eq3 + __popcll(e4);
    const bool sel0 = (k0 < T) || ((k0 == T) && (__popcll(e0 & below) < need));
    const bool sel1 = (NSL > 1) && ((k1 < T) || ((k1 == T) && (eq0 + __popcll(e1 & below) < need)));
    const bool sel2 = (NSL > 2) && ((k2 < T) || ((k2 == T) && (eq1 + __popcll(e2 & below) < need)));
    const bool sel3 = (NSL > 3) && ((k3 < T) || ((k3 == T) && (eq2 + __popcll(e3 & below) < need)));
    const bool sel4 = (NSL > 4) && ((k4 < T) || ((k4 == T) && (eq3 + __popcll(e4 & below) < need)));
    const bool sel5 = (NSL > 5) && ((k5 < T) || ((k5 == T) && (eq4 + __popcll(__ballot(k5 == T) & below) < need)));
    const unsigned long long s0 = __ballot(sel0);
    const unsigned long long s1 = __ballot(sel1);
    const unsigned long long s2 = __ballot(sel2);
    const unsigned long long s3 = __ballot(sel3);
    const unsigned long long s4 = __ballot(sel4);
    const unsigned long long s5 = __ballot(sel5);
    const int c0 = __popcll(s0), c1 = c0 + __popcll(s1), c2 = c1 + __popcll(s2),
              c3 = c2 + __popcll(s3), c4 = c3 + __popcll(s4);
    if (lane < 16) widxW[lane] = min(start, Ns - 1);   // fallback, len<16 never in practice
    __builtin_amdgcn_wave_barrier();
    if (sel0) widxW[__popcll(s0 & below)] = start + lane;
    if (NSL > 1 && sel1) widxW[c0 + __popcll(s1 & below)] = start + lane + 64;
    if (NSL > 2 && sel2) widxW[c1 + __popcll(s2 & below)] = start + lane + 128;
    if (NSL > 3 && sel3) widxW[c2 + __popcll(s3 & below)] = start + lane + 192;
    if (NSL > 4 && sel4) widxW[c3 + __popcll(s4 & below)] = start + lane + 256;
    if (NSL > 5 && sel5) widxW[c4 + __popcll(s5 & below)] = start + lane + 320;
    __builtin_amdgcn_wave_barrier();
}

// ---------------------------------------------------------------------------
// ONE node per wave. Distances from the quad-major transposed array
// (coalesced vector loads); neighbor rows from the row-major array.
// 4-ARY ballot bisection: 3 monotone thresholds/iter -> <=16 iterations
// (was 31 binary). Invariant each iter: count(<=hi) >= 16 and
// count(<=lo-1) < 16, so exit lo == T = 16th smallest key, identical to the
// binary version. Bounded for-loop (defensive). Exact tie-order compaction
// unchanged. No block barriers anywhere.
// ---------------------------------------------------------------------------
template <int NSL>
__device__ __forceinline__ void conv_single(
    float4 x0, float4 x1, float4 x2, float4 x3,
    float4 x4, float4 x5, float4 x6, float4 x7,
    float ni, int start, int len,
    const float* __restrict__ srcf, const float4* __restrict__ srcT4,
    const float* __restrict__ srcn, int Ns,
    const float* __restrict__ W, const float* __restrict__ Bc,
    float4 w20, float4 w21, float4 w22, float4 w23,
    float4 w24, float4 w25, float4 w26, float4 w27,
    float4* __restrict__ sNbr, int* __restrict__ widxW,
    int lane, float& vOut)
{
    unsigned k0 = 0xFFFFFFFFu, k1 = 0xFFFFFFFFu, k2 = 0xFFFFFFFFu,
             k3 = 0xFFFFFFFFu, k4 = 0xFFFFFFFFu, k5 = 0xFFFFFFFFu;
    k0 = slot_key_T4(0, lane, start, len, Ns, srcT4, srcn, ni, x0, x1, x2, x3, x4, x5, x6, x7);
    if (NSL > 1 && len > 64)  k1 = slot_key_T4(1, lane, start, len, Ns, srcT4, srcn, ni, x0, x1, x2, x3, x4, x5, x6, x7);
    if (NSL > 2 && len > 128) k2 = slot_key_T4(2, lane, start, len, Ns, srcT4, srcn, ni, x0, x1, x2, x3, x4, x5, x6, x7);
    if (NSL > 3 && len > 192) k3 = slot_key_T4(3, lane, start, len, Ns, srcT4, srcn, ni, x0, x1, x2, x3, x4, x5, x6, x7);
    if (NSL > 4 && len > 256) k4 = slot_key_T4(4, lane, start, len, Ns, srcT4, srcn, ni, x0, x1, x2, x3, x4, x5, x6, x7);
    if (NSL > 5 && len > 320) k5 = slot_key_T4(5, lane, start, len, Ns, srcT4, srcn, ni, x0, x1, x2, x3, x4, x5, x6, x7);

    // 4-ary bisection over the key value space. All valid keys have bit31
    // set, so lo seeds at 0x80000000. Wave-uniform lo/hi (ballot-derived).
    unsigned lo = 0x80000000u, hi = 0xFFFFFFFFu;
#pragma unroll 1
    for (int it = 0; it < 20 && lo < hi; ++it) {
        const unsigned span = hi - lo;
        const unsigned q  = span >> 2;
        const unsigned m1 = lo + q;
        const unsigned m2 = lo + (span >> 1);
        const unsigned m3 = hi - q;
        int c1 = __popcll(__ballot(k0 <= m1));
        int c2 = __popcll(__ballot(k0 <= m2));
        int c3 = __popcll(__ballot(k0 <= m3));
        if (NSL > 1) { c1 += __popcll(__ballot(k1 <= m1)); c2 += __popcll(__ballot(k1 <= m2)); c3 += __popcll(__ballot(k1 <= m3)); }
        if (NSL > 2) { c1 += __popcll(__ballot(k2 <= m1)); c2 += __popcll(__ballot(k2 <= m2)); c3 += __popcll(__ballot(k2 <= m3)); }
        if (NSL > 3) { c1 += __popcll(__ballot(k3 <= m1)); c2 += __popcll(__ballot(k3 <= m2)); c3 += __popcll(__ballot(k3 <= m3)); }
        if (NSL > 4) { c1 += __popcll(__ballot(k4 <= m1)); c2 += __popcll(__ballot(k4 <= m2)); c3 += __popcll(__ballot(k4 <= m3)); }
        if (NSL > 5) { c1 += __popcll(__ballot(k5 <= m1)); c2 += __popcll(__ballot(k5 <= m2)); c3 += __popcll(__ballot(k5 <= m3)); }
        if (c1 >= 16) hi = m1;
        else if (c2 >= 16) { lo = m1 + 1; hi = m2; }
        else if (c3 >= 16) { lo = m2 + 1; hi = m3; }
        else lo = m3 + 1;   // count(<=hi)>=16 invariant => interval stays valid
    }

    select_compact<NSL>(k0, k1, k2, k3, k4, k5, lo, start, Ns, widxW, lane);

    const int c = lane & 31;
    const int n0 = lane >> 3, qq = lane & 7;
    const int n1 = n0 + 8;
    int j0 = widxW[n0]; j0 = ((unsigned)j0 < (unsigned)Ns) ? j0 : 0;
    int j1 = widxW[n1]; j1 = ((unsigned)j1 < (unsigned)Ns) ? j1 : 0;
    const float4* S = reinterpret_cast<const float4*>(srcf);
    const float4 r0 = S[(size_t)j0 * 8 + qq];
    const float4 r1 = S[(size_t)j1 * 8 + qq];

    float base = Bc[c];
    base = wdot4(W, c, 0, x0, base); base = wdot4(W, c, 1, x1, base);
    base = wdot4(W, c, 2, x2, base); base = wdot4(W, c, 3, x3, base);
    base = wdot4(W, c, 4, x4, base); base = wdot4(W, c, 5, x5, base);
    base = wdot4(W, c, 6, x6, base); base = wdot4(W, c, 7, x7, base);
    float dd = 0.0f;
    dd = dot4(x0, w20, dd); dd = dot4(x1, w21, dd); dd = dot4(x2, w22, dd); dd = dot4(x3, w23, dd);
    dd = dot4(x4, w24, dd); dd = dot4(x5, w25, dd); dd = dot4(x6, w26, dd); dd = dot4(x7, w27, dd);
    const float cbase = base - dd;

    sNbr[n0 * 8 + qq] = r0;
    sNbr[n1 * 8 + qq] = r1;
    __builtin_amdgcn_wave_barrier();

    const int half = lane >> 5;
    float vm = -__builtin_huge_valf();
#pragma unroll 1
    for (int r = 0; r < 8; ++r) {
        const float4* nb = sNbr + (2 * r + half) * 8;
        float acc = cbase;
        acc = dot4(nb[0], w20, acc);
        acc = dot4(nb[1], w21, acc);
        acc = dot4(nb[2], w22, acc);
        acc = dot4(nb[3], w23, acc);
        acc = dot4(nb[4], w24, acc);
        acc = dot4(nb[5], w25, acc);
        acc = dot4(nb[6], w26, acc);
        acc = dot4(nb[7], w27, acc);
        vm = fmaxf(vm, LRELU(acc));
    }
    vm = fmaxf(vm, __shfl_xor(vm, 32));
    vOut = vm;
}

// ---------------------------------------------------------------------------
// Kernel 1: both MLP2 encoders + sq norms + group-offset tables + quad-major
// transposed feature copies (encT4[q*Nn + node] = float4 of dims 4q..4q+3).
// ---------------------------------------------------------------------------
__launch_bounds__(256)
__global__ void encode_kernel(const float* __restrict__ x_pfc, const float* __restrict__ x_vtx,
                              const int* __restrict__ bpfc, const int* __restrict__ bvtx,
                              const float* __restrict__ pw1, const float* __restrict__ pb1,
                              const float* __restrict__ pw2, const float* __restrict__ pb2,
                              const float* __restrict__ vw1, const float* __restrict__ vb1,
                              const float* __restrict__ vw2, const float* __restrict__ vb2,
                              float* __restrict__ pfc_enc, float* __restrict__ pfc_norm,
                              float* __restrict__ vtx_enc, float* __restrict__ vtx_norm,
                              float* __restrict__ pfc_encT4, float* __restrict__ vtx_encT4,
                              int* __restrict__ goff_pfc, int* __restrict__ goff_vtx) {
    __shared__ float h1s[8][32];
    const int t = threadIdx.x;
    const int c = t & 31;
    const int nl = t >> 5;

    if (blockIdx.x == 0) {
        if (t < 33) goff_pfc[t] = lower_bound_i(bpfc, 8192, t);
        else if (t >= 64 && t < 97) goff_vtx[t - 64] = lower_bound_i(bvtx, 2048, t - 64);
    }

    const bool is_pfc = (blockIdx.x < 1024);
    const int node = (is_pfc ? blockIdx.x : (blockIdx.x - 1024)) * 8 + nl;
    const int din = is_pfc ? 7 : 4;
    const int Nn = is_pfc ? 8192 : 2048;
    const float* __restrict__ xin = is_pfc ? (x_pfc + node * 7) : (x_vtx + node * 4);
    const float* __restrict__ w1 = is_pfc ? pw1 : vw1;
    const float* __restrict__ b1 = is_pfc ? pb1 : vb1;
    const float* __restrict__ w2 = is_pfc ? pw2 : vw2;
    const float* __restrict__ b2 = is_pfc ? pb2 : vb2;
    float* __restrict__ enc   = is_pfc ? pfc_enc : vtx_enc;
    float* __restrict__ encT4 = is_pfc ? pfc_encT4 : vtx_encT4;
    float* __restrict__ nrm   = is_pfc ? pfc_norm : vtx_norm;

    float h1 = b1[c];
    for (int d = 0; d < din; ++d) h1 = fmaf(xin[d], w1[d * 32 + c], h1);
    h1 = LRELU(h1);
    h1s[nl][c] = h1;
    __syncthreads();

    float h2 = b2[c];
#pragma unroll
    for (int d = 0; d < 32; ++d) h2 = fmaf(h1s[nl][d], w2[d * 32 + c], h2);
    h2 = LRELU(h2);
    enc[node * 32 + c] = h2;
    // quad-major transpose: dim c -> quad c>>2, elem c&3
    encT4[((size_t)(c >> 2) * Nn + node) * 4 + (c & 3)] = h2;

    float s = h2 * h2;
#pragma unroll
    for (int m = 16; m >= 1; m >>= 1) s += __shfl_xor(s, m);
    if (c == 0) nrm[node] = s;
}

// ---------------------------------------------------------------------------
// Kernel 2: fused conv1 + conv2 + output MLP. ONE node per WAVE, TWO
// independent waves per 128-thread block (wave-indexed LDS, zero block
// barriers). R2/R3 post-mortem: 64-thread workgroups pin VGPR=64 on this
// toolchain regardless of launch_bounds/waves_per_eu attrs -> ~100-reg live
// state spilled -> 164MB scratch writes, spill-BW-bound at 2.1TB/s. The
// 128-thread + __launch_bounds__(128) config is empirically proven (round
// 0) to allocate VGPR=128 with ZERO spills. Keeps: finer drain granularity
// (4096 blocks x 2 nodes), halved per-wave serial chain, 4-ary bisection.
// ---------------------------------------------------------------------------
__launch_bounds__(128)
__global__ void fused_conv_mlp_kernel(
    const float* __restrict__ pfc_enc, const float4* __restrict__ pfc_encT4,
    const float* __restrict__ n_pfc,
    const float* __restrict__ vtx_enc, const float4* __restrict__ vtx_encT4,
    const float* __restrict__ n_vtx,
    const int* __restrict__ bpfc,
    const int* __restrict__ goff_pfc, const int* __restrict__ goff_vtx,
    const float* __restrict__ W, const float* __restrict__ Bc,
    const float* __restrict__ ow1, const float* __restrict__ ob1,
    const float* __restrict__ ow2, const float* __restrict__ ob2,
    const float* __restrict__ ow3, const float* __restrict__ ob3,
    const float* __restrict__ ow4, const float* __restrict__ ob4,
    float* __restrict__ dout, int N)
{
    __shared__ __align__(16) float4 sNbr[2][128];   // [wave]
    __shared__ int widx[2][16];
    __shared__ __align__(16) float sRow[2][32];
    __shared__ float sEx1[2][64];

    const int t = threadIdx.x;
    const int lane = t & 63;
    const int w = t >> 6;
    const int b = blockIdx.x;              // 4096 blocks x 2 nodes (1/wave)
    const int xcd = b & 7, chunk = b >> 3;
    const int i = xcd * 1024 + chunk * 2 + w;   // XCD-contiguous node slices
    const int c = lane & 31;

    float4* sNbrW = &sNbr[w][0];
    int* widxW = &widx[w][0];
    float* sRowW = &sRow[w][0];
    float* sEx1W = &sEx1[w][0];

    // W2 column (rows 32..63, col c) into 8 float4 regs (L2-hot broadcast)
    const float4 w20 = make_float4(W[32 * 32 + c], W[33 * 32 + c], W[34 * 32 + c], W[35 * 32 + c]);
    const float4 w21 = make_float4(W[36 * 32 + c], W[37 * 32 + c], W[38 * 32 + c], W[39 * 32 + c]);
    const float4 w22 = make_float4(W[40 * 32 + c], W[41 * 32 + c], W[42 * 32 + c], W[43 * 32 + c]);
    const float4 w23 = make_float4(W[44 * 32 + c], W[45 * 32 + c], W[46 * 32 + c], W[47 * 32 + c]);
    const float4 w24 = make_float4(W[48 * 32 + c], W[49 * 32 + c], W[50 * 32 + c], W[51 * 32 + c]);
    const float4 w25 = make_float4(W[52 * 32 + c], W[53 * 32 + c], W[54 * 32 + c], W[55 * 32 + c]);
    const float4 w26 = make_float4(W[56 * 32 + c], W[57 * 32 + c], W[58 * 32 + c], W[59 * 32 + c]);
    const float4 w27 = make_float4(W[60 * 32 + c], W[61 * 32 + c], W[62 * 32 + c], W[63 * 32 + c]);

    const int g = bpfc[i];

    // ---- conv1: src = dst = pfc ----
    const float4* x = reinterpret_cast<const float4*>(pfc_enc + (size_t)i * 32);
    const float4 a0 = x[0], a1 = x[1], a2 = x[2], a3 = x[3],
                 a4 = x[4], a5 = x[5], a6 = x[6], a7 = x[7];
    const float ni = n_pfc[i];
    const int s1 = goff_pfc[g], len1 = min(goff_pfc[g + 1] - s1, 384);

    float v1;
    if (((len1 + 63) >> 6) <= 4)
        conv_single<4>(a0, a1, a2, a3, a4, a5, a6, a7, ni, s1, len1,
                       pfc_enc, pfc_encT4, n_pfc, 8192, W, Bc,
                       w20, w21, w22, w23, w24, w25, w26, w27,
                       sNbrW, widxW, lane, v1);
    else
        conv_single<6>(a0, a1, a2, a3, a4, a5, a6, a7, ni, s1, len1,
                       pfc_enc, pfc_encT4, n_pfc, 8192, W, Bc,
                       w20, w21, w22, w23, w24, w25, w26, w27,
                       sNbrW, widxW, lane, v1);

    if (lane < 32) sRowW[lane] = v1;
    float nf = v1 * v1;
#pragma unroll
    for (int m = 16; m >= 1; m >>= 1) nf += __shfl_xor(nf, m);
    __builtin_amdgcn_wave_barrier();

    // ---- conv2: dst = feats1 row (wave-private LDS), src = vtx ----
    const float4* f = reinterpret_cast<const float4*>(sRowW);
    const float4 y0 = f[0], y1 = f[1], y2 = f[2], y3 = f[3],
                 y4 = f[4], y5 = f[5], y6 = f[6], y7 = f[7];
    const int s2 = goff_vtx[g], len2 = min(goff_vtx[g + 1] - s2, 128);

    float v2;
    conv_single<2>(y0, y1, y2, y3, y4, y5, y6, y7, nf, s2, len2,
                   vtx_enc, vtx_encT4, n_vtx, 2048, W, Bc,
                   w20, w21, w22, w23, w24, w25, w26, w27,
                   sNbrW, widxW, lane, v2);

    // ---- output MLP 32 -> 64 -> 32 -> 4 -> 1 (lrelu each), wave-private ----
    if (lane < 32) sRowW[lane] = v2;
    __builtin_amdgcn_wave_barrier();

    // layer 1: 64 outputs, one per lane (weights from global, L2-hot)
    {
        float h1 = ob1[lane];
#pragma unroll
        for (int d = 0; d < 32; ++d) h1 = fmaf(sRowW[d], ow1[d * 64 + lane], h1);
        sEx1W[lane] = LRELU(h1);
    }
    __builtin_amdgcn_wave_barrier();

    // layer 2: 32 outputs (both halves duplicate)
    {
        float h2 = ob2[c];
#pragma unroll
        for (int d = 0; d < 64; ++d) h2 = fmaf(sEx1W[d], ow2[d * 32 + c], h2);
        if (lane < 32) sRowW[lane] = LRELU(h2);
    }
    __builtin_amdgcn_wave_barrier();

    // layers 3+4 (tiny): wave-uniform weight reads -> scalar loads
    {
        float a0_ = ob3[0], a1_ = ob3[1], a2_ = ob3[2], a3_ = ob3[3];
#pragma unroll
        for (int d = 0; d < 32; ++d) {
            const float e = sRowW[d];
            a0_ = fmaf(e, ow3[d * 4 + 0], a0_);
            a1_ = fmaf(e, ow3[d * 4 + 1], a1_);
            a2_ = fmaf(e, ow3[d * 4 + 2], a2_);
            a3_ = fmaf(e, ow3[d * 4 + 3], a3_);
        }
        a0_ = LRELU(a0_); a1_ = LRELU(a1_); a2_ = LRELU(a2_); a3_ = LRELU(a3_);
        float o = ob4[0];
        o = fmaf(a0_, ow4[0], o); o = fmaf(a1_, ow4[1], o);
        o = fmaf(a2_, ow4[2], o); o = fmaf(a3_, ow4[3], o);
        o = LRELU(o);

        if (lane == 0) dout[i] = o;                     // output 0
        if (lane == 1) dout[N + i] = (float)g;          // output 1
    }
}

// ---------------------------------------------------------------------------
extern "C" void kernel_launch(void* const* d_in, const int* in_sizes, int n_in,
                              void* d_out, int out_size, void* d_ws, size_t ws_size,
                              hipStream_t stream) {
    const float* x_pfc     = (const float*)d_in[0];
    const float* x_vtx     = (const float*)d_in[1];
    const int*   batch_pfc = (const int*)d_in[2];
    const int*   batch_vtx = (const int*)d_in[3];
    const float* pfc_w1 = (const float*)d_in[4];
    const float* pfc_b1 = (const float*)d_in[5];
    const float* pfc_w2 = (const float*)d_in[6];
    const float* pfc_b2 = (const float*)d_in[7];
    const float* vtx_w1 = (const float*)d_in[8];
    const float* vtx_b1 = (const float*)d_in[9];
    const float* vtx_w2 = (const float*)d_in[10];
    const float* vtx_b2 = (const float*)d_in[11];
    const float* conv_w = (const float*)d_in[12];
    const float* conv_b = (const float*)d_in[13];
    const float* out_w1 = (const float*)d_in[14];
    const float* out_b1 = (const float*)d_in[15];
    const float* out_w2 = (const float*)d_in[16];
    const float* out_b2 = (const float*)d_in[17];
    const float* out_w3 = (const float*)d_in[18];
    const float* out_b3 = (const float*)d_in[19];
    const float* out_w4 = (const float*)d_in[20];
    const float* out_b4 = (const float*)d_in[21];

    const int N_PFC = 8192;

    float* ws = (float*)d_ws;
    float* pfc_enc   = ws;                     // 8192*32
    float* vtx_enc   = ws + 262144;            // 2048*32
    float* n_pfc     = ws + 327680;            // 8192
    float* n_vtx     = ws + 335872;            // 2048
    int*   goff_pfc  = (int*)(ws + 337920);    // 33 (+pad)
    int*   goff_vtx  = (int*)(ws + 337984);    // 33 (+pad)
    float* pfc_encT4 = ws + 338048;            // 8 quads * 8192 * 4 = 262144
    float* vtx_encT4 = ws + 600192;            // 8 * 2048 * 4 = 65536  (total 665728 floats)

    encode_kernel<<<1280, 256, 0, stream>>>(x_pfc, x_vtx, batch_pfc, batch_vtx,
                                            pfc_w1, pfc_b1, pfc_w2, pfc_b2,
                                            vtx_w1, vtx_b1, vtx_w2, vtx_b2,
                                            pfc_enc, n_pfc, vtx_enc, n_vtx,
                                            pfc_encT4, vtx_encT4,
                                            goff_pfc, goff_vtx);

    fused_conv_mlp_kernel<<<4096, 128, 0, stream>>>(
        pfc_enc, (const float4*)pfc_encT4, n_pfc,
        vtx_enc, (const float4*)vtx_encT4, n_vtx,
        batch_pfc, goff_pfc, goff_vtx, conv_w, conv_b,
        out_w1, out_b1, out_w2, out_b2, out_w3, out_b3, out_w4, out_b4,
        (float*)d_out, N_PFC);
}

// Round 5
// 156.339 us; speedup vs baseline: 1.3366x; 1.3366x over previous
//
#include <hip/hip_runtime.h>
#include <hip/hip_bf16.h>

#define LRELU(val) ((val) >= 0.0f ? (val) : 0.01f * (val))

__device__ __forceinline__ float dot4(float4 a, float4 b, float acc) {
    return fmaf(a.x, b.x, fmaf(a.y, b.y, fmaf(a.z, b.z, fmaf(a.w, b.w, acc))));
}

__device__ __forceinline__ float wdot4(const float* __restrict__ wbase, int c, int q,
                                       float4 a, float acc) {
    acc = fmaf(a.x, wbase[(4 * q + 0) * 32 + c], acc);
    acc = fmaf(a.y, wbase[(4 * q + 1) * 32 + c], acc);
    acc = fmaf(a.z, wbase[(4 * q + 2) * 32 + c], acc);
    acc = fmaf(a.w, wbase[(4 * q + 3) * 32 + c], acc);
    return acc;
}

__device__ inline int lower_bound_i(const int* __restrict__ a, int n, int v) {
    int lo = 0, hi = n;
    while (lo < hi) {
        int m = (lo + hi) >> 1;
        if (a[m] < v) lo = m + 1; else hi = m;
    }
    return lo;
}

// Sortable 32-bit distance key from the QUAD-MAJOR transposed array:
// srcT4[q*Ns + j] = float4 of dims 4q..4q+3 of node j. Lane L reads node
// j = start+L+64s -> consecutive lanes, 16B stride = 16 lines/instr AND only
// 8 dwordx4 issues. dot accumulation = validated dot4 order.
__device__ __forceinline__ unsigned slot_key_T4(
    int s, int lane, int start, int len, int Ns,
    const float4* __restrict__ srcT4, const float* __restrict__ srcn, float ni,
    float4 x0, float4 x1, float4 x2, float4 x3,
    float4 x4, float4 x5, float4 x6, float4 x7)
{
    const int o = lane + 64 * s;
    const bool valid = o < len;
    const int j = valid ? (start + o) : min(start, Ns - 1);
    float dot = 0.0f;
    dot = dot4(srcT4[0 * Ns + j], x0, dot);
    dot = dot4(srcT4[1 * Ns + j], x1, dot);
    dot = dot4(srcT4[2 * Ns + j], x2, dot);
    dot = dot4(srcT4[3 * Ns + j], x3, dot);
    dot = dot4(srcT4[4 * Ns + j], x4, dot);
    dot = dot4(srcT4[5 * Ns + j], x5, dot);
    dot = dot4(srcT4[6 * Ns + j], x6, dot);
    dot = dot4(srcT4[7 * Ns + j], x7, dot);
    const float d2 = (ni + srcn[j]) - 2.0f * dot;   // reference distance formula
    unsigned u = __float_as_uint(d2);
    u = (d2 < 0.0f) ? ~u : (u | 0x80000000u);       // monotone float->uint map
    return valid ? u : 0xFFFFFFFFu;
}

// Membership + compaction for one node (exact lax.top_k tie semantics).
template <int NSL>
__device__ __forceinline__ void select_compact(
    unsigned k0, unsigned k1, unsigned k2, unsigned k3, unsigned k4, unsigned k5,
    unsigned T, int start, int Ns, int* __restrict__ widxW, int lane)
{
    const unsigned long long below = (1ull << lane) - 1ull;
    int m = __popcll(__ballot(k0 < T));
    if (NSL > 1) m += __popcll(__ballot(k1 < T));
    if (NSL > 2) m += __popcll(__ballot(k2 < T));
    if (NSL > 3) m += __popcll(__ballot(k3 < T));
    if (NSL > 4) m += __popcll(__ballot(k4 < T));
    if (NSL > 5) m += __popcll(__ballot(k5 < T));
    const int need = 16 - m;
    const unsigned long long e0 = __ballot(k0 == T);
    const unsigned long long e1 = (NSL > 1) ? __ballot(k1 == T) : 0ull;
    const unsigned long long e2 = (NSL > 2) ? __ballot(k2 == T) : 0ull;
    const unsigned long long e3 = (NSL > 3) ? __ballot(k3 == T) : 0ull;
    const unsigned long long e4 = (NSL > 4) ? __ballot(k4 == T) : 0ull;
    const int eq0 = __popcll(e0), eq1 = eq0 + __popcll(e1), eq2 = eq1 + __popcll(e2),
              eq3 = eq2 + __popcll(e3), eq4 = eq3 + __popcll(e4);
    const bool sel0 = (k0 < T) || ((k0 == T) && (__popcll(e0 & below) < need));
    const bool sel1 = (NSL > 1) && ((k1 < T) || ((k1 == T) && (eq0 + __popcll(e1 & below) < need)));
    const bool sel2 = (NSL > 2) && ((k2 < T) || ((k2 == T) && (eq1 + __popcll(e2 & below) < need)));
    const bool sel3 = (NSL > 3) && ((k3 < T) || ((k3 == T) && (eq2 + __popcll(e3 & below) < need)));
    const bool sel4 = (NSL > 4) && ((k4 < T) || ((k4 == T) && (eq3 + __popcll(e4 & below) < need)));
    const bool sel5 = (NSL > 5) && ((k5 < T) || ((k5 == T) && (eq4 + __popcll(__ballot(k5 == T) & below) < need)));
    const unsigned long long s0 = __ballot(sel0);
    const unsigned long long s1 = __ballot(sel1);
    const unsigned long long s2 = __ballot(sel2);
    const unsigned long long s3 = __ballot(sel3);
    const unsigned long long s4 = __ballot(sel4);
    const unsigned long long s5 = __ballot(sel5);
    const int c0 = __popcll(s0), c1 = c0 + __popcll(s1), c2 = c1 + __popcll(s2),
              c3 = c2 + __popcll(s3), c4 = c3 + __popcll(s4);
    if (lane < 16) widxW[lane] = min(start, Ns - 1);   // fallback, len<16 never in practice
    __builtin_amdgcn_wave_barrier();
    if (sel0) widxW[__popcll(s0 & below)] = start + lane;
    if (NSL > 1 && sel1) widxW[c0 + __popcll(s1 & below)] = start + lane + 64;
    if (NSL > 2 && sel2) widxW[c1 + __popcll(s2 & below)] = start + lane + 128;
    if (NSL > 3 && sel3) widxW[c2 + __popcll(s3 & below)] = start + lane + 192;
    if (NSL > 4 && sel4) widxW[c3 + __popcll(s4 & below)] = start + lane + 256;
    if (NSL > 5 && sel5) widxW[c4 + __popcll(s5 & below)] = start + lane + 320;
    __builtin_amdgcn_wave_barrier();
}

// ---------------------------------------------------------------------------
// TWO independent nodes per wave, all phases interleaved (R0 structure —
// validated at 71.4us; R4 proved the A/B interleave is worth more than
// finer drain granularity). SINGLE change vs R0: 4-ARY ballot bisection
// (3 monotone thresholds/node/iter -> <=16 iters instead of 31 binary).
// Invariant each iter: count(<=hi) >= 16, count(<=lo-1) < 16 -> exit
// lo == T = 16th-smallest key, identical to binary. Bounded loop
// (defensive). Exact tie-order compaction unchanged. No block barriers.
// ---------------------------------------------------------------------------
template <int NSL>
__device__ __forceinline__ void conv_pair(
    float4 ax0, float4 ax1, float4 ax2, float4 ax3,
    float4 ax4, float4 ax5, float4 ax6, float4 ax7,
    float niA, int startA, int lenA,
    float4 bx0, float4 bx1, float4 bx2, float4 bx3,
    float4 bx4, float4 bx5, float4 bx6, float4 bx7,
    float niB, int startB, int lenB,
    const float* __restrict__ srcf, const float4* __restrict__ srcT4,
    const float* __restrict__ srcn, int Ns,
    const float* __restrict__ W, const float* __restrict__ Bc,
    float4 w20, float4 w21, float4 w22, float4 w23,
    float4 w24, float4 w25, float4 w26, float4 w27,
    float4* __restrict__ sNbrA, float4* __restrict__ sNbrB,
    int* __restrict__ widxA, int* __restrict__ widxB,
    int lane, float& vOutA, float& vOutB)
{
    unsigned kA0 = 0xFFFFFFFFu, kA1 = 0xFFFFFFFFu, kA2 = 0xFFFFFFFFu,
             kA3 = 0xFFFFFFFFu, kA4 = 0xFFFFFFFFu, kA5 = 0xFFFFFFFFu;
    unsigned kB0 = 0xFFFFFFFFu, kB1 = 0xFFFFFFFFu, kB2 = 0xFFFFFFFFu,
             kB3 = 0xFFFFFFFFu, kB4 = 0xFFFFFFFFu, kB5 = 0xFFFFFFFFu;
    kA0 = slot_key_T4(0, lane, startA, lenA, Ns, srcT4, srcn, niA, ax0, ax1, ax2, ax3, ax4, ax5, ax6, ax7);
    kB0 = slot_key_T4(0, lane, startB, lenB, Ns, srcT4, srcn, niB, bx0, bx1, bx2, bx3, bx4, bx5, bx6, bx7);
    if (NSL > 1) {
        if (lenA > 64)  kA1 = slot_key_T4(1, lane, startA, lenA, Ns, srcT4, srcn, niA, ax0, ax1, ax2, ax3, ax4, ax5, ax6, ax7);
        if (lenB > 64)  kB1 = slot_key_T4(1, lane, startB, lenB, Ns, srcT4, srcn, niB, bx0, bx1, bx2, bx3, bx4, bx5, bx6, bx7);
    }
    if (NSL > 2) {
        if (lenA > 128) kA2 = slot_key_T4(2, lane, startA, lenA, Ns, srcT4, srcn, niA, ax0, ax1, ax2, ax3, ax4, ax5, ax6, ax7);
        if (lenB > 128) kB2 = slot_key_T4(2, lane, startB, lenB, Ns, srcT4, srcn, niB, bx0, bx1, bx2, bx3, bx4, bx5, bx6, bx7);
    }
    if (NSL > 3) {
        if (lenA > 192) kA3 = slot_key_T4(3, lane, startA, lenA, Ns, srcT4, srcn, niA, ax0, ax1, ax2, ax3, ax4, ax5, ax6, ax7);
        if (lenB > 192) kB3 = slot_key_T4(3, lane, startB, lenB, Ns, srcT4, srcn, niB, bx0, bx1, bx2, bx3, bx4, bx5, bx6, bx7);
    }
    if (NSL > 4) {
        if (lenA > 256) kA4 = slot_key_T4(4, lane, startA, lenA, Ns, srcT4, srcn, niA, ax0, ax1, ax2, ax3, ax4, ax5, ax6, ax7);
        if (lenB > 256) kB4 = slot_key_T4(4, lane, startB, lenB, Ns, srcT4, srcn, niB, bx0, bx1, bx2, bx3, bx4, bx5, bx6, bx7);
    }
    if (NSL > 5) {
        if (lenA > 320) kA5 = slot_key_T4(5, lane, startA, lenA, Ns, srcT4, srcn, niA, ax0, ax1, ax2, ax3, ax4, ax5, ax6, ax7);
        if (lenB > 320) kB5 = slot_key_T4(5, lane, startB, lenB, Ns, srcT4, srcn, niB, bx0, bx1, bx2, bx3, bx4, bx5, bx6, bx7);
    }

    // 4-ary bisection, A and B interleaved (6*NSL independent ballots/iter).
    // All valid keys have bit31 set -> lo seeds at 0x80000000.
    unsigned loA = 0x80000000u, hiA = 0xFFFFFFFFu, loB = 0x80000000u, hiB = 0xFFFFFFFFu;
#pragma unroll 1
    for (int it = 0; it < 20 && (loA < hiA || loB < hiB); ++it) {
        const unsigned spanA = hiA - loA, spanB = hiB - loB;
        const unsigned qA = spanA >> 2, qB = spanB >> 2;
        const unsigned mA1 = loA + qA, mB1 = loB + qB;
        const unsigned mA2 = loA + (spanA >> 1), mB2 = loB + (spanB >> 1);
        const unsigned mA3 = hiA - qA, mB3 = hiB - qB;
        int cA1 = __popcll(__ballot(kA0 <= mA1));
        int cA2 = __popcll(__ballot(kA0 <= mA2));
        int cA3 = __popcll(__ballot(kA0 <= mA3));
        int cB1 = __popcll(__ballot(kB0 <= mB1));
        int cB2 = __popcll(__ballot(kB0 <= mB2));
        int cB3 = __popcll(__ballot(kB0 <= mB3));
        if (NSL > 1) {
            cA1 += __popcll(__ballot(kA1 <= mA1)); cA2 += __popcll(__ballot(kA1 <= mA2)); cA3 += __popcll(__ballot(kA1 <= mA3));
            cB1 += __popcll(__ballot(kB1 <= mB1)); cB2 += __popcll(__ballot(kB1 <= mB2)); cB3 += __popcll(__ballot(kB1 <= mB3));
        }
        if (NSL > 2) {
            cA1 += __popcll(__ballot(kA2 <= mA1)); cA2 += __popcll(__ballot(kA2 <= mA2)); cA3 += __popcll(__ballot(kA2 <= mA3));
            cB1 += __popcll(__ballot(kB2 <= mB1)); cB2 += __popcll(__ballot(kB2 <= mB2)); cB3 += __popcll(__ballot(kB2 <= mB3));
        }
        if (NSL > 3) {
            cA1 += __popcll(__ballot(kA3 <= mA1)); cA2 += __popcll(__ballot(kA3 <= mA2)); cA3 += __popcll(__ballot(kA3 <= mA3));
            cB1 += __popcll(__ballot(kB3 <= mB1)); cB2 += __popcll(__ballot(kB3 <= mB2)); cB3 += __popcll(__ballot(kB3 <= mB3));
        }
        if (NSL > 4) {
            cA1 += __popcll(__ballot(kA4 <= mA1)); cA2 += __popcll(__ballot(kA4 <= mA2)); cA3 += __popcll(__ballot(kA4 <= mA3));
            cB1 += __popcll(__ballot(kB4 <= mB1)); cB2 += __popcll(__ballot(kB4 <= mB2)); cB3 += __popcll(__ballot(kB4 <= mB3));
        }
        if (NSL > 5) {
            cA1 += __popcll(__ballot(kA5 <= mA1)); cA2 += __popcll(__ballot(kA5 <= mA2)); cA3 += __popcll(__ballot(kA5 <= mA3));
            cB1 += __popcll(__ballot(kB5 <= mB1)); cB2 += __popcll(__ballot(kB5 <= mB2)); cB3 += __popcll(__ballot(kB5 <= mB3));
        }
        if (loA < hiA) {
            if (cA1 >= 16) hiA = mA1;
            else if (cA2 >= 16) { loA = mA1 + 1; hiA = mA2; }
            else if (cA3 >= 16) { loA = mA2 + 1; hiA = mA3; }
            else loA = mA3 + 1;   // count(<=hiA)>=16 invariant keeps interval valid
        }
        if (loB < hiB) {
            if (cB1 >= 16) hiB = mB1;
            else if (cB2 >= 16) { loB = mB1 + 1; hiB = mB2; }
            else if (cB3 >= 16) { loB = mB2 + 1; hiB = mB3; }
            else loB = mB3 + 1;
        }
    }

    select_compact<NSL>(kA0, kA1, kA2, kA3, kA4, kA5, loA, startA, Ns, widxA, lane);
    select_compact<NSL>(kB0, kB1, kB2, kB3, kB4, kB5, loB, startB, Ns, widxB, lane);

    const int c = lane & 31;
    const int n0 = lane >> 3, qq = lane & 7;
    const int n1 = n0 + 8;
    int jA0 = widxA[n0]; jA0 = ((unsigned)jA0 < (unsigned)Ns) ? jA0 : 0;
    int jA1 = widxA[n1]; jA1 = ((unsigned)jA1 < (unsigned)Ns) ? jA1 : 0;
    int jB0 = widxB[n0]; jB0 = ((unsigned)jB0 < (unsigned)Ns) ? jB0 : 0;
    int jB1 = widxB[n1]; jB1 = ((unsigned)jB1 < (unsigned)Ns) ? jB1 : 0;
    const float4* S = reinterpret_cast<const float4*>(srcf);
    const float4 rA0 = S[(size_t)jA0 * 8 + qq];
    const float4 rA1 = S[(size_t)jA1 * 8 + qq];
    const float4 rB0 = S[(size_t)jB0 * 8 + qq];
    const float4 rB1 = S[(size_t)jB1 * 8 + qq];

    float baseA = Bc[c];
    baseA = wdot4(W, c, 0, ax0, baseA); baseA = wdot4(W, c, 1, ax1, baseA);
    baseA = wdot4(W, c, 2, ax2, baseA); baseA = wdot4(W, c, 3, ax3, baseA);
    baseA = wdot4(W, c, 4, ax4, baseA); baseA = wdot4(W, c, 5, ax5, baseA);
    baseA = wdot4(W, c, 6, ax6, baseA); baseA = wdot4(W, c, 7, ax7, baseA);
    float dA = 0.0f;
    dA = dot4(ax0, w20, dA); dA = dot4(ax1, w21, dA); dA = dot4(ax2, w22, dA); dA = dot4(ax3, w23, dA);
    dA = dot4(ax4, w24, dA); dA = dot4(ax5, w25, dA); dA = dot4(ax6, w26, dA); dA = dot4(ax7, w27, dA);
    const float cbaseA = baseA - dA;

    float baseB = Bc[c];
    baseB = wdot4(W, c, 0, bx0, baseB); baseB = wdot4(W, c, 1, bx1, baseB);
    baseB = wdot4(W, c, 2, bx2, baseB); baseB = wdot4(W, c, 3, bx3, baseB);
    baseB = wdot4(W, c, 4, bx4, baseB); baseB = wdot4(W, c, 5, bx5, baseB);
    baseB = wdot4(W, c, 6, bx6, baseB); baseB = wdot4(W, c, 7, bx7, baseB);
    float dB = 0.0f;
    dB = dot4(bx0, w20, dB); dB = dot4(bx1, w21, dB); dB = dot4(bx2, w22, dB); dB = dot4(bx3, w23, dB);
    dB = dot4(bx4, w24, dB); dB = dot4(bx5, w25, dB); dB = dot4(bx6, w26, dB); dB = dot4(bx7, w27, dB);
    const float cbaseB = baseB - dB;

    sNbrA[n0 * 8 + qq] = rA0;
    sNbrA[n1 * 8 + qq] = rA1;
    sNbrB[n0 * 8 + qq] = rB0;
    sNbrB[n1 * 8 + qq] = rB1;
    __builtin_amdgcn_wave_barrier();

    const int half = lane >> 5;
    float vmA = -__builtin_huge_valf(), vmB = -__builtin_huge_valf();
#pragma unroll 1
    for (int r = 0; r < 8; ++r) {
        const float4* nA = sNbrA + (2 * r + half) * 8;
        const float4* nB = sNbrB + (2 * r + half) * 8;
        float accA = cbaseA, accB = cbaseB;
        accA = dot4(nA[0], w20, accA); accB = dot4(nB[0], w20, accB);
        accA = dot4(nA[1], w21, accA); accB = dot4(nB[1], w21, accB);
        accA = dot4(nA[2], w22, accA); accB = dot4(nB[2], w22, accB);
        accA = dot4(nA[3], w23, accA); accB = dot4(nB[3], w23, accB);
        accA = dot4(nA[4], w24, accA); accB = dot4(nB[4], w24, accB);
        accA = dot4(nA[5], w25, accA); accB = dot4(nB[5], w25, accB);
        accA = dot4(nA[6], w26, accA); accB = dot4(nB[6], w26, accB);
        accA = dot4(nA[7], w27, accA); accB = dot4(nB[7], w27, accB);
        vmA = fmaxf(vmA, LRELU(accA));
        vmB = fmaxf(vmB, LRELU(accB));
    }
    vmA = fmaxf(vmA, __shfl_xor(vmA, 32));
    vmB = fmaxf(vmB, __shfl_xor(vmB, 32));
    vOutA = vmA;
    vOutB = vmB;
}

// ---------------------------------------------------------------------------
// Kernel 1: both MLP2 encoders + sq norms + group-offset tables + quad-major
// transposed feature copies (encT4[q*Nn + node] = float4 of dims 4q..4q+3).
// ---------------------------------------------------------------------------
__launch_bounds__(256)
__global__ void encode_kernel(const float* __restrict__ x_pfc, const float* __restrict__ x_vtx,
                              const int* __restrict__ bpfc, const int* __restrict__ bvtx,
                              const float* __restrict__ pw1, const float* __restrict__ pb1,
                              const float* __restrict__ pw2, const float* __restrict__ pb2,
                              const float* __restrict__ vw1, const float* __restrict__ vb1,
                              const float* __restrict__ vw2, const float* __restrict__ vb2,
                              float* __restrict__ pfc_enc, float* __restrict__ pfc_norm,
                              float* __restrict__ vtx_enc, float* __restrict__ vtx_norm,
                              float* __restrict__ pfc_encT4, float* __restrict__ vtx_encT4,
                              int* __restrict__ goff_pfc, int* __restrict__ goff_vtx) {
    __shared__ float h1s[8][32];
    const int t = threadIdx.x;
    const int c = t & 31;
    const int nl = t >> 5;

    if (blockIdx.x == 0) {
        if (t < 33) goff_pfc[t] = lower_bound_i(bpfc, 8192, t);
        else if (t >= 64 && t < 97) goff_vtx[t - 64] = lower_bound_i(bvtx, 2048, t - 64);
    }

    const bool is_pfc = (blockIdx.x < 1024);
    const int node = (is_pfc ? blockIdx.x : (blockIdx.x - 1024)) * 8 + nl;
    const int din = is_pfc ? 7 : 4;
    const int Nn = is_pfc ? 8192 : 2048;
    const float* __restrict__ xin = is_pfc ? (x_pfc + node * 7) : (x_vtx + node * 4);
    const float* __restrict__ w1 = is_pfc ? pw1 : vw1;
    const float* __restrict__ b1 = is_pfc ? pb1 : vb1;
    const float* __restrict__ w2 = is_pfc ? pw2 : vw2;
    const float* __restrict__ b2 = is_pfc ? pb2 : vb2;
    float* __restrict__ enc   = is_pfc ? pfc_enc : vtx_enc;
    float* __restrict__ encT4 = is_pfc ? pfc_encT4 : vtx_encT4;
    float* __restrict__ nrm   = is_pfc ? pfc_norm : vtx_norm;

    float h1 = b1[c];
    for (int d = 0; d < din; ++d) h1 = fmaf(xin[d], w1[d * 32 + c], h1);
    h1 = LRELU(h1);
    h1s[nl][c] = h1;
    __syncthreads();

    float h2 = b2[c];
#pragma unroll
    for (int d = 0; d < 32; ++d) h2 = fmaf(h1s[nl][d], w2[d * 32 + c], h2);
    h2 = LRELU(h2);
    enc[node * 32 + c] = h2;
    // quad-major transpose: dim c -> quad c>>2, elem c&3
    encT4[((size_t)(c >> 2) * Nn + node) * 4 + (c & 3)] = h2;

    float s = h2 * h2;
#pragma unroll
    for (int m = 16; m >= 1; m >>= 1) s += __shfl_xor(s, m);
    if (c == 0) nrm[node] = s;
}

// ---------------------------------------------------------------------------
// Kernel 2: fused conv1 + conv2 + output MLP. TWO nodes per wave (R0
// structure: A/B interleave = wave-internal ILP, empirically worth more
// than R4's finer granularity), 128-thr blocks, ZERO block barriers.
// MLP weights read straight from GLOBAL in the tail (L2-hot, wave-uniform
// -> s_load). LDS ~10KB. Plain __launch_bounds__(128): R0-proven VGPR=128,
// zero spills. Single change vs R0: 4-ary bisection.
// ---------------------------------------------------------------------------
__launch_bounds__(128)
__global__ void fused_conv_mlp_kernel(
    const float* __restrict__ pfc_enc, const float4* __restrict__ pfc_encT4,
    const float* __restrict__ n_pfc,
    const float* __restrict__ vtx_enc, const float4* __restrict__ vtx_encT4,
    const float* __restrict__ n_vtx,
    const int* __restrict__ bpfc,
    const int* __restrict__ goff_pfc, const int* __restrict__ goff_vtx,
    const float* __restrict__ W, const float* __restrict__ Bc,
    const float* __restrict__ ow1, const float* __restrict__ ob1,
    const float* __restrict__ ow2, const float* __restrict__ ob2,
    const float* __restrict__ ow3, const float* __restrict__ ob3,
    const float* __restrict__ ow4, const float* __restrict__ ob4,
    float* __restrict__ dout, int N)
{
    __shared__ __align__(16) float4 sNbr[2][2][128];   // [wave][node]
    __shared__ int widx[2][2][16];
    __shared__ __align__(16) float sRow[2][2][32];
    __shared__ float sEx1[2][2][64];

    const int t = threadIdx.x;
    const int lane = t & 63;
    const int w = t >> 6;
    const int b = blockIdx.x;              // 2048 blocks x 4 nodes
    const int xcd = b & 7, chunk = b >> 3;
    const int iA = xcd * 1024 + chunk * 4 + w * 2;
    const int iB = iA + 1;
    const int c = lane & 31;

    // W2 column (rows 32..63, col c) into 8 float4 regs (L2-hot broadcast)
    const float4 w20 = make_float4(W[32 * 32 + c], W[33 * 32 + c], W[34 * 32 + c], W[35 * 32 + c]);
    const float4 w21 = make_float4(W[36 * 32 + c], W[37 * 32 + c], W[38 * 32 + c], W[39 * 32 + c]);
    const float4 w22 = make_float4(W[40 * 32 + c], W[41 * 32 + c], W[42 * 32 + c], W[43 * 32 + c]);
    const float4 w23 = make_float4(W[44 * 32 + c], W[45 * 32 + c], W[46 * 32 + c], W[47 * 32 + c]);
    const float4 w24 = make_float4(W[48 * 32 + c], W[49 * 32 + c], W[50 * 32 + c], W[51 * 32 + c]);
    const float4 w25 = make_float4(W[52 * 32 + c], W[53 * 32 + c], W[54 * 32 + c], W[55 * 32 + c]);
    const float4 w26 = make_float4(W[56 * 32 + c], W[57 * 32 + c], W[58 * 32 + c], W[59 * 32 + c]);
    const float4 w27 = make_float4(W[60 * 32 + c], W[61 * 32 + c], W[62 * 32 + c], W[63 * 32 + c]);

    float4* sNbrA = &sNbr[w][0][0];
    float4* sNbrB = &sNbr[w][1][0];
    int* widxA = &widx[w][0][0];
    int* widxB = &widx[w][1][0];

    const int gA = bpfc[iA], gB = bpfc[iB];

    // ---- conv1: src = dst = pfc ----
    const float4* xA = reinterpret_cast<const float4*>(pfc_enc + (size_t)iA * 32);
    const float4 a0 = xA[0], a1 = xA[1], a2 = xA[2], a3 = xA[3],
                 a4 = xA[4], a5 = xA[5], a6 = xA[6], a7 = xA[7];
    const float4* xB = reinterpret_cast<const float4*>(pfc_enc + (size_t)iB * 32);
    const float4 b0 = xB[0], b1 = xB[1], b2 = xB[2], b3 = xB[3],
                 b4 = xB[4], b5 = xB[5], b6 = xB[6], b7 = xB[7];
    const float niA = n_pfc[iA], niB = n_pfc[iB];
    const int s1A = goff_pfc[gA], len1A = min(goff_pfc[gA + 1] - s1A, 384);
    const int s1B = goff_pfc[gB], len1B = min(goff_pfc[gB + 1] - s1B, 384);

    float v1A, v1B;
    {
        const int nsl = (max(len1A, len1B) + 63) >> 6;
        if (nsl <= 4)
            conv_pair<4>(a0, a1, a2, a3, a4, a5, a6, a7, niA, s1A, len1A,
                         b0, b1, b2, b3, b4, b5, b6, b7, niB, s1B, len1B,
                         pfc_enc, pfc_encT4, n_pfc, 8192, W, Bc,
                         w20, w21, w22, w23, w24, w25, w26, w27,
                         sNbrA, sNbrB, widxA, widxB, lane, v1A, v1B);
        else
            conv_pair<6>(a0, a1, a2, a3, a4, a5, a6, a7, niA, s1A, len1A,
                         b0, b1, b2, b3, b4, b5, b6, b7, niB, s1B, len1B,
                         pfc_enc, pfc_encT4, n_pfc, 8192, W, Bc,
                         w20, w21, w22, w23, w24, w25, w26, w27,
                         sNbrA, sNbrB, widxA, widxB, lane, v1A, v1B);
    }

    if (lane < 32) { sRow[w][0][lane] = v1A; sRow[w][1][lane] = v1B; }
    float nfA = v1A * v1A, nfB = v1B * v1B;
#pragma unroll
    for (int m = 16; m >= 1; m >>= 1) { nfA += __shfl_xor(nfA, m); nfB += __shfl_xor(nfB, m); }
    __builtin_amdgcn_wave_barrier();

    // ---- conv2: dst = feats1 rows (wave-private LDS), src = vtx ----
    const float4* fA = reinterpret_cast<const float4*>(&sRow[w][0][0]);
    const float4 ya0 = fA[0], ya1 = fA[1], ya2 = fA[2], ya3 = fA[3],
                 ya4 = fA[4], ya5 = fA[5], ya6 = fA[6], ya7 = fA[7];
    const float4* fB = reinterpret_cast<const float4*>(&sRow[w][1][0]);
    const float4 yb0 = fB[0], yb1 = fB[1], yb2 = fB[2], yb3 = fB[3],
                 yb4 = fB[4], yb5 = fB[5], yb6 = fB[6], yb7 = fB[7];
    const int s2A = goff_vtx[gA], len2A = min(goff_vtx[gA + 1] - s2A, 128);
    const int s2B = goff_vtx[gB], len2B = min(goff_vtx[gB + 1] - s2B, 128);

    float v2A, v2B;
    conv_pair<2>(ya0, ya1, ya2, ya3, ya4, ya5, ya6, ya7, nfA, s2A, len2A,
                 yb0, yb1, yb2, yb3, yb4, yb5, yb6, yb7, nfB, s2B, len2B,
                 vtx_enc, vtx_encT4, n_vtx, 2048, W, Bc,
                 w20, w21, w22, w23, w24, w25, w26, w27,
                 sNbrA, sNbrB, widxA, widxB, lane, v2A, v2B);

    // ---- output MLP 32 -> 64 -> 32 -> 4 -> 1 (lrelu each), wave-private ----
    if (lane < 32) { sRow[w][0][lane] = v2A; sRow[w][1][lane] = v2B; }
    __builtin_amdgcn_wave_barrier();

    // layer 1: 64 outputs per node, one per lane (weights from global, L2-hot)
    {
        float h1a = ob1[lane], h1b = h1a;
#pragma unroll
        for (int d = 0; d < 32; ++d) {
            const float wv = ow1[d * 64 + lane];
            h1a = fmaf(sRow[w][0][d], wv, h1a);
            h1b = fmaf(sRow[w][1][d], wv, h1b);
        }
        sEx1[w][0][lane] = LRELU(h1a);
        sEx1[w][1][lane] = LRELU(h1b);
    }
    __builtin_amdgcn_wave_barrier();

    // layer 2: 32 outputs per node (both halves duplicate)
    {
        float h2a = ob2[c], h2b = h2a;
#pragma unroll
        for (int d = 0; d < 64; ++d) {
            const float wv = ow2[d * 32 + c];
            h2a = fmaf(sEx1[w][0][d], wv, h2a);
            h2b = fmaf(sEx1[w][1][d], wv, h2b);
        }
        if (lane < 32) { sRow[w][0][lane] = LRELU(h2a); sRow[w][1][lane] = LRELU(h2b); }
    }
    __builtin_amdgcn_wave_barrier();

    // layers 3+4 (tiny): wave-uniform weight reads -> scalar loads
    {
        float aa0 = ob3[0], aa1 = ob3[1], aa2 = ob3[2], aa3 = ob3[3];
        float bb0 = aa0, bb1 = aa1, bb2 = aa2, bb3 = aa3;
#pragma unroll
        for (int d = 0; d < 32; ++d) {
            const float ea = sRow[w][0][d], eb = sRow[w][1][d];
            const float w0v = ow3[d * 4 + 0], w1v = ow3[d * 4 + 1],
                        w2v = ow3[d * 4 + 2], w3v = ow3[d * 4 + 3];
            aa0 = fmaf(ea, w0v, aa0); bb0 = fmaf(eb, w0v, bb0);
            aa1 = fmaf(ea, w1v, aa1); bb1 = fmaf(eb, w1v, bb1);
            aa2 = fmaf(ea, w2v, aa2); bb2 = fmaf(eb, w2v, bb2);
            aa3 = fmaf(ea, w3v, aa3); bb3 = fmaf(eb, w3v, bb3);
        }
        aa0 = LRELU(aa0); aa1 = LRELU(aa1); aa2 = LRELU(aa2); aa3 = LRELU(aa3);
        bb0 = LRELU(bb0); bb1 = LRELU(bb1); bb2 = LRELU(bb2); bb3 = LRELU(bb3);
        const float q0 = ow4[0], q1 = ow4[1], q2 = ow4[2], q3 = ow4[3], bz = ob4[0];
        float oA = bz, oB = bz;
        oA = fmaf(aa0, q0, oA); oA = fmaf(aa1, q1, oA); oA = fmaf(aa2, q2, oA); oA = fmaf(aa3, q3, oA);
        oB = fmaf(bb0, q0, oB); oB = fmaf(bb1, q1, oB); oB = fmaf(bb2, q2, oB); oB = fmaf(bb3, q3, oB);
        oA = LRELU(oA); oB = LRELU(oB);

        if (lane == 0) { dout[iA] = oA; dout[iB] = oB; }              // output 0
        if (lane == 1) { dout[N + iA] = (float)gA; dout[N + iB] = (float)gB; }  // output 1
    }
}

// ---------------------------------------------------------------------------
extern "C" void kernel_launch(void* const* d_in, const int* in_sizes, int n_in,
                              void* d_out, int out_size, void* d_ws, size_t ws_size,
                              hipStream_t stream) {
    const float* x_pfc     = (const float*)d_in[0];
    const float* x_vtx     = (const float*)d_in[1];
    const int*   batch_pfc = (const int*)d_in[2];
    const int*   batch_vtx = (const int*)d_in[3];
    const float* pfc_w1 = (const float*)d_in[4];
    const float* pfc_b1 = (const float*)d_in[5];
    const float* pfc_w2 = (const float*)d_in[6];
    const float* pfc_b2 = (const float*)d_in[7];
    const float* vtx_w1 = (const float*)d_in[8];
    const float* vtx_b1 = (const float*)d_in[9];
    const float* vtx_w2 = (const float*)d_in[10];
    const float* vtx_b2 = (const float*)d_in[11];
    const float* conv_w = (const float*)d_in[12];
    const float* conv_b = (const float*)d_in[13];
    const float* out_w1 = (const float*)d_in[14];
    const float* out_b1 = (const float*)d_in[15];
    const float* out_w2 = (const float*)d_in[16];
    const float* out_b2 = (const float*)d_in[17];
    const float* out_w3 = (const float*)d_in[18];
    const float* out_b3 = (const float*)d_in[19];
    const float* out_w4 = (const float*)d_in[20];
    const float* out_b4 = (const float*)d_in[21];

    const int N_PFC = 8192;

    float* ws = (float*)d_ws;
    float* pfc_enc   = ws;                     // 8192*32
    float* vtx_enc   = ws + 262144;            // 2048*32
    float* n_pfc     = ws + 327680;            // 8192
    float* n_vtx     = ws + 335872;            // 2048
    int*   goff_pfc  = (int*)(ws + 337920);    // 33 (+pad)
    int*   goff_vtx  = (int*)(ws + 337984);    // 33 (+pad)
    float* pfc_encT4 = ws + 338048;            // 8 quads * 8192 * 4 = 262144
    float* vtx_encT4 = ws + 600192;            // 8 * 2048 * 4 = 65536  (total 665728 floats)

    encode_kernel<<<1280, 256, 0, stream>>>(x_pfc, x_vtx, batch_pfc, batch_vtx,
                                            pfc_w1, pfc_b1, pfc_w2, pfc_b2,
                                            vtx_w1, vtx_b1, vtx_w2, vtx_b2,
                                            pfc_enc, n_pfc, vtx_enc, n_vtx,
                                            pfc_encT4, vtx_encT4,
                                            goff_pfc, goff_vtx);

    fused_conv_mlp_kernel<<<2048, 128, 0, stream>>>(
        pfc_enc, (const float4*)pfc_encT4, n_pfc,
        vtx_enc, (const float4*)vtx_encT4, n_vtx,
        batch_pfc, goff_pfc, goff_vtx, conv_w, conv_b,
        out_w1, out_b1, out_w2, out_b2, out_w3, out_b3, out_w4, out_b4,
        (float*)d_out, N_PFC);
}